// Round 15
// baseline (646.023 us; speedup 1.0000x reference)
//
#include <hip/hip_runtime.h>
#include <math.h>

#define TLEN 32768
#define NFR  513
#define TP   576          // padded frame count
#define PI_F 3.14159265358979323846f

typedef unsigned short u16;
typedef unsigned int   u32;
typedef _Float16 h16;
typedef h16  half8  __attribute__((ext_vector_type(8)));
typedef h16  half4  __attribute__((ext_vector_type(4)));
typedef float f32x4 __attribute__((ext_vector_type(4)));

// float-unit offsets in workspace
#define OFF_TST  0         // Tst h16 [144][128]: stft DFT table (window folded)
#define OFF_TI   9216      // Tist h16 [128][160]: istft table, invden folded
#define OFF_B2P  19456     // b2p h16 [512][64]
#define OFF_R    35840     // hpart h16 [64][513][256] THEN w216 h16 [33280][256]
#define OFF_HT   4295680   // hT16 h16 [8][576][256], chunk-swizzled
#define OFF_X16  4885504   // X16 h16 [128][576][136]
#define OFF_Y16  9899008   // Y16 h16 [128][513][136]
#define OFF_W116 14364160  // w116s h16 [128ci][2 half][256co x 64k swizzled]
// end: 16,461,312 floats = 65.8 MB

#define F4(p) (*reinterpret_cast<const float4*>(p))
#define GLDS(gsrc, ldst) __builtin_amdgcn_global_load_lds( \
    (const __attribute__((address_space(1))) void*)(gsrc),  \
    (__attribute__((address_space(3))) void*)(ldst), 16, 0, 0)

__device__ __forceinline__ u16 pkh(float v) { return __builtin_bit_cast(u16, (h16)v); }

__global__ void dfc_tables(float* __restrict__ ws) {
  int tid = threadIdx.x;
  u16* Ts = (u16*)(ws + OFF_TST);
  for (int idx = tid; idx < 144*128; idx += 256) {
    int c = idx >> 7, k = idx & 127;
    float v = 0.0f;
    if (c < 136) {
      int p = c / 68, fb = c - p*68;
      if (fb <= 64) {
        float wk = 0.5f*(1.0f - cosf(2.0f*PI_F*(float)k/128.0f));
        float ang = 2.0f*PI_F*(float)((fb*k) & 127)/128.0f;
        v = (p == 0) ? wk*cosf(ang) : -wk*sinf(ang);
      }
    }
    Ts[idx] = pkh(v);
  }
  u16* Ti = (u16*)(ws + OFF_TI);
  for (int idx = tid; idx < 128*160; idx += 256) {
    int k = idx / 160, c = idx - k*160;
    float v = 0.0f;
    if (c < 136) {
      int p = c / 68, fb = c - p*68;
      if (fb <= 64) {
        float wk = 0.5f*(1.0f - cosf(2.0f*PI_F*(float)k/128.0f));
        float cf = (fb == 0 || fb == 64) ? 1.0f : 2.0f;
        float sc = (1.0f/128.0f)*wk*cf;
        float ang = 2.0f*PI_F*(float)((fb*k) & 127)/128.0f;
        int j = k & 63;
        float w0 = 0.5f*(1.0f - cosf(2.0f*PI_F*(float)j/128.0f));
        float w1 = 0.5f*(1.0f - cosf(2.0f*PI_F*(float)(j+64)/128.0f));
        float inv = 1.0f/fmaxf(w0*w0 + w1*w1, 1e-11f);
        v = ((p == 0) ? sc*cosf(ang) : -sc*sinf(ang)) * inv;
      }
    }
    Ti[idx] = pkh(v);
  }
}

// w116s: per (ci, half): 16 KB h16 block [256co][64k], XOR-swizzled
__launch_bounds__(256)
__global__ void dfc_prep_w1(const float* __restrict__ w1, u16* __restrict__ w116) {
  int idx = blockIdx.x*256 + threadIdx.x;           // < 524288
  int k8 = idx & 15, rc = idx >> 4;
  int co = rc & 255, ci = rc >> 8;
  const float* src = w1 + ((size_t)(co*128 + ci)*128 + k8*8);
  float4 a = F4(src), b = F4(src + 4);
  half8 hv;
  hv[0]=(h16)a.x; hv[1]=(h16)a.y; hv[2]=(h16)a.z; hv[3]=(h16)a.w;
  hv[4]=(h16)b.x; hv[5]=(h16)b.y; hv[6]=(h16)b.z; hv[7]=(h16)b.w;
  size_t dst = (size_t)ci*32768 + (k8 >> 3)*16384
             + co*64 + ((((k8 & 7) ^ (co & 7))) << 3);
  *(half8*)((h16*)w116 + dst) = hv;
}

// w216[row][c] = fp16(w2[row][c]) with in-row chunk swizzle: chunk c/8 ^ (fb&7)
__launch_bounds__(256)
__global__ void dfc_prep_w2(const float* __restrict__ w2, u16* __restrict__ w216) {
  int idx = blockIdx.x*256 + threadIdx.x;           // < 1064960
  int cc = idx & 31, r = idx >> 5;
  int fb = r % 65;
  const float* src = w2 + (size_t)r*256 + cc*8;
  float4 a = F4(src), b = F4(src + 4);
  half8 hv;
  hv[0]=(h16)a.x; hv[1]=(h16)a.y; hv[2]=(h16)a.z; hv[3]=(h16)a.w;
  hv[4]=(h16)b.x; hv[5]=(h16)b.y; hv[6]=(h16)b.z; hv[7]=(h16)b.w;
  *(half8*)((h16*)w216 + (size_t)r*256 + ((cc ^ (fb & 7)) << 3)) = hv;
}

// b2p[((o*16+i)*2+p)*64 + fb] = fp16(b2[((p*16+o)*16+i)*65 + fb]), fb<64
__launch_bounds__(256)
__global__ void dfc_prep_b2(const float* __restrict__ b2, u16* __restrict__ b2p) {
  int idx = blockIdx.x*256 + threadIdx.x;           // < 32768
  int fb = idx & 63, r = idx >> 6;
  int p = r & 1, oi = r >> 1, o = oi >> 4, i = oi & 15;
  ((h16*)b2p)[idx] = (h16)b2[(size_t)((p*16 + o)*16 + i)*65 + fb];
}

// conv1 v8 (round-13 verbatim): A via GLDS ring-3 (1 barrier/phase, counted vmcnt),
// B reg-staged fp16 LDS. 512 thr, 256co x 64t, 32 phases.
__launch_bounds__(512, 2)
__global__ void dfc_conv1(const float* __restrict__ cond, const u16* __restrict__ w116,
                          u16* __restrict__ hpart) {
  extern __shared__ __align__(16) char LDS[];
  const int flat = (blockIdx.z*8 + blockIdx.y)*9 + blockIdx.x;
  const int kc = flat & 7;
  const int rest = flat >> 3;                       // 0..71
  const int b = rest / 9, tile = rest - b*9;
  const int t0 = tile*64;
  const int tid = threadIdx.x;
  const int wave = tid >> 6, lane = tid & 63;
  const int l15 = lane & 15, g16 = lane >> 4;
  const int gbase = t0*64 - 64;                     // f32 index
  const bool edge = (tile == 0) || (tile == 8);
  const char* wbB = (const char*)w116 + (size_t)kc*16*65536;
  const float* condB = cond + (size_t)(b*128 + kc*16)*TLEN;

  float4 rv[3];
  auto loadB = [&](int ci) {
    const float* cb = condB + (size_t)ci*TLEN;
    if (!edge) {
      rv[0] = F4(cb + gbase + 4*tid);
      rv[1] = F4(cb + gbase + 4*(512 + tid));
      rv[2] = F4(cb + gbase + 4*(1024 + (tid & 15)));
    } else {
      #pragma unroll
      for (int r = 0; r < 3; ++r) {
        int q = (r < 2) ? (r*512 + tid) : (1024 + (tid & 15));
        int g0 = gbase + 4*q;
        float4 v;
        v.x = (g0   >= 0 && g0   < TLEN) ? cb[g0]   : 0.f;
        v.y = (g0+1 >= 0 && g0+1 < TLEN) ? cb[g0+1] : 0.f;
        v.z = (g0+2 >= 0 && g0+2 < TLEN) ? cb[g0+2] : 0.f;
        v.w = (g0+3 >= 0 && g0+3 < TLEN) ? cb[g0+3] : 0.f;
        rv[r] = v;
      }
    }
  };
  auto writeB = [&](int bslot) {
    u32* seg = (u32*)(LDS + 98304 + bslot*8448);
    #pragma unroll
    for (int r = 0; r < 3; ++r) {
      if (r < 2 || tid < 16) {
        int q = (r < 2) ? (r*512 + tid) : (1024 + tid);
        int s2 = 2*q;
        int ph = s2 ^ (((s2 >> 5) & 7) << 2);
        uint2 pr;
        pr.x = (u32)pkh(rv[r].x) | ((u32)pkh(rv[r].y) << 16);
        pr.y = (u32)pkh(rv[r].z) | ((u32)pkh(rv[r].w) << 16);
        *reinterpret_cast<uint2*>(&seg[ph]) = pr;
      }
    }
  };
  auto stageA = [&](int p, int slot) {
    const char* src = wbB + (size_t)(p >> 1)*65536 + (p & 1)*32768 + wave*4096 + lane*16;
    char* dst = LDS + slot*32768 + wave*4096;
    GLDS(src,        dst);
    GLDS(src + 1024, dst + 1024);
    GLDS(src + 2048, dst + 2048);
    GLDS(src + 3072, dst + 3072);
  };

  loadB(0);
  stageA(0, 0); stageA(1, 1);
  if (edge) asm volatile("s_waitcnt vmcnt(0)" ::: "memory");
  else      asm volatile("s_waitcnt vmcnt(8)" ::: "memory");
  writeB(0);
  loadB(1);

  f32x4 acc[2][4] = {};
  for (int p = 0; p < 32; ++p) {
    const int ci = p >> 1, h = p & 1, sl = p % 3;
    if (edge || p >= 30) asm volatile("s_waitcnt vmcnt(0)" ::: "memory");
    else                 asm volatile("s_waitcnt vmcnt(7)" ::: "memory");
    asm volatile("s_waitcnt lgkmcnt(0)" ::: "memory");
    __builtin_amdgcn_s_barrier();
    __builtin_amdgcn_sched_barrier(0);
    if (p + 2 < 32) stageA(p + 2, (p + 2) % 3);
    if (h == 0 && ci + 1 < 16) {
      if (edge) asm volatile("s_waitcnt vmcnt(0)" ::: "memory");
      else      asm volatile("s_waitcnt vmcnt(4)" ::: "memory");
      writeB((ci + 1) & 1);
      if (ci + 2 < 16) loadB(ci + 2);
    }
    const char* Ab = LDS + sl*32768;
    const u32* seg = (const u32*)(LDS + 98304 + (ci & 1)*8448);
    __builtin_amdgcn_s_setprio(1);
    #pragma unroll
    for (int ks = 0; ks < 2; ++ks) {
      half8 Bf[4];
      #pragma unroll
      for (int nt = 0; nt < 4; ++nt) {
        int s2 = 32*(nt*16 + l15) + 32*h + 16*ks + 4*g16;
        int ph = s2 ^ (((s2 >> 5) & 7) << 2);
        Bf[nt] = *(const half8*)&seg[ph];
      }
      #pragma unroll
      for (int mi = 0; mi < 2; ++mi) {
        int co = wave*32 + mi*16 + l15;
        half8 Af = *(const half8*)(Ab + co*128 + (((ks*4 + g16) ^ (co & 7)) << 4));
        #pragma unroll
        for (int nt = 0; nt < 4; ++nt)
          acc[mi][nt] = __builtin_amdgcn_mfma_f32_16x16x32_f16(Af, Bf[nt], acc[mi][nt], 0,0,0);
      }
    }
    __builtin_amdgcn_s_setprio(0);
  }
  h16* hp = (h16*)hpart;
  #pragma unroll
  for (int mi = 0; mi < 2; ++mi) {
    const int co0 = wave*32 + mi*16 + g16*4;
    #pragma unroll
    for (int nt = 0; nt < 4; ++nt) {
      int t = t0 + nt*16 + l15;
      if (t < NFR) {
        half4 v;
        v[0]=(h16)acc[mi][nt][0]; v[1]=(h16)acc[mi][nt][1];
        v[2]=(h16)acc[mi][nt][2]; v[3]=(h16)acc[mi][nt][3];
        *(half4*)(hp + ((size_t)(kc*8 + b)*NFR + t)*256 + co0) = v;
      }
    }
  }
}

// reduce 8 partials + b1 -> hT16[b][t][c] fp16, chunk-swizzled (c/8 ^ (t&7))
__launch_bounds__(256)
__global__ void dfc_hred(const u16* __restrict__ hpart, const float* __restrict__ b1,
                         u16* __restrict__ hT16) {
  int idx = blockIdx.x*256 + threadIdx.x;            // < 131328
  int b = idx / 16416, r = idx % 16416;
  int t = r >> 5, cc = r & 31;
  float s[8];
  float4 ba = F4(&b1[cc*8]), bb = F4(&b1[cc*8 + 4]);
  s[0]=ba.x; s[1]=ba.y; s[2]=ba.z; s[3]=ba.w; s[4]=bb.x; s[5]=bb.y; s[6]=bb.z; s[7]=bb.w;
  const h16* hp = (const h16*)hpart;
  #pragma unroll
  for (int kc = 0; kc < 8; ++kc) {
    half8 hv = *(const half8*)(hp + ((size_t)(kc*8 + b)*NFR + t)*256 + cc*8);
    #pragma unroll
    for (int j = 0; j < 8; ++j) s[j] += (float)hv[j];
  }
  half8 o;
  #pragma unroll
  for (int j = 0; j < 8; ++j) o[j] = (h16)s[j];
  *(half8*)((h16*)hT16 + ((size_t)b*TP + t)*256 + ((cc ^ (t & 7)) << 3)) = o;
}

// stft v3 (MFMA): X[c=p*68+fb][t] = Tst[144x128] * frames[128k x 96t]
__launch_bounds__(256)
__global__ void dfc_stft(const float* __restrict__ x, const float* __restrict__ wsp,
                         u16* __restrict__ X16) {
  __shared__ __align__(16) u32 winu[3104];
  const int tile = blockIdx.x, row = blockIdx.y;
  const int t0 = (tile < 5) ? tile*96 : 417;
  const int tid = threadIdx.x;
  const int wave = tid >> 6, lane = tid & 63;
  const int wm = wave >> 1, wn = wave & 1;
  const int l15 = lane & 15, g16 = lane >> 4;
  const int gbase = t0*64 - 64;
  const bool edge = (tile == 0) || (tile == 5);
  const float* xb = x + (size_t)row*TLEN;

  #pragma unroll
  for (int r = 0; r < 7; ++r) {
    if (r < 6 || tid < 16) {
      int q = (r < 6) ? (tid + 256*r) : (1536 + tid);
      float4 v;
      if (!edge) {
        v = F4(xb + gbase + 4*q);
      } else {
        int g0 = gbase + 4*q;
        float e[4];
        #pragma unroll
        for (int j = 0; j < 4; ++j) {
          int g = g0 + j;
          int sidx = (g < 0) ? -g : ((g >= TLEN) ? (2*TLEN - 2 - g) : g);
          e[j] = xb[sidx];
        }
        v.x = e[0]; v.y = e[1]; v.z = e[2]; v.w = e[3];
      }
      int s2 = 2*q;
      int ph = s2 ^ (((s2 >> 5) & 7) << 2);
      uint2 pr;
      pr.x = (u32)pkh(v.x) | ((u32)pkh(v.y) << 16);
      pr.y = (u32)pkh(v.z) | ((u32)pkh(v.w) << 16);
      *reinterpret_cast<uint2*>(&winu[ph]) = pr;
    }
  }
  __syncthreads();
  const h16* Ts = (const h16*)(wsp + OFF_TST);
  f32x4 acc[5][3] = {};
  #pragma unroll
  for (int ks = 0; ks < 4; ++ks) {
    half8 Bf[3];
    #pragma unroll
    for (int nt = 0; nt < 3; ++nt) {
      int tl = (wn*3 + nt)*16 + l15;
      int s2 = 32*tl + 16*ks + 4*g16;
      int ph = s2 ^ (((s2 >> 5) & 7) << 2);
      Bf[nt] = *(const half8*)&winu[ph];
    }
    #pragma unroll
    for (int m = 0; m < 5; ++m) {
      int mi = wm*4 + m;
      half8 Af = *(const half8*)(Ts + (size_t)(mi*16 + l15)*128 + ks*32 + g16*8);
      #pragma unroll
      for (int nt = 0; nt < 3; ++nt)
        acc[m][nt] = __builtin_amdgcn_mfma_f32_16x16x32_f16(Af, Bf[nt], acc[m][nt], 0,0,0);
    }
  }
  h16* Xh = (h16*)X16;
  #pragma unroll
  for (int m = 0; m < 5; ++m) {
    int c0 = (wm*4 + m)*16 + g16*4;
    if (c0 < 136) {
      #pragma unroll
      for (int nt = 0; nt < 3; ++nt) {
        int t = t0 + (wn*3 + nt)*16 + l15;
        half4 v;
        v[0]=(h16)acc[m][nt][0]; v[1]=(h16)acc[m][nt][1];
        v[2]=(h16)acc[m][nt][2]; v[3]=(h16)acc[m][nt][3];
        *(half4*)(Xh + ((size_t)row*TP + t)*136 + c0) = v;
      }
    }
  }
}

// conv2y v7.1: ring-3 A (48KB -> 3 blocks/CU); stage issued AFTER entry barrier
// (fixes v7's overwrite race on Al[(s+2)%3] = buffer read at s-1);
// X/b2 counted register prefetch at kk0. Waits (FIFO-simulated):
// kk0/kk1 vmcnt(24), kk2/kk3 vmcnt(8), s63 vmcnt(0).
__launch_bounds__(256, 3)
__global__ void dfc_conv2y(const u16* __restrict__ w216, const u16* __restrict__ hT16,
                           const u16* __restrict__ b2p, const u16* __restrict__ X16,
                           u16* __restrict__ Y16) {
  __shared__ __align__(16) char Al[3][16384];
  const int flat = (blockIdx.z*16 + blockIdx.y)*6 + blockIdx.x;
  const int b  = flat & 7;
  const int r2 = flat >> 3;
  const int o  = r2 / 6;
  const int t0 = (r2 - o*6) * 96;
  const int tid = threadIdx.x;
  const int wave = tid >> 6, lane = tid & 63;
  const int wp = wave >> 1, wn = wave & 1;
  const int l15 = lane & 15, g16 = lane >> 4;
  const int lrow8 = lane >> 3, lcol = (lane & 7)*16;
  const char* wb = (const char*)w216;

  half8 Breg[3][8];
  #pragma unroll
  for (int nt = 0; nt < 3; ++nt) {
    int t = t0 + wn*48 + nt*16 + l15;
    const h16* hrow = (const h16*)hT16 + ((size_t)b*TP + t)*256;
    #pragma unroll
    for (int ks = 0; ks < 8; ++ks)
      Breg[nt][ks] = *(const half8*)(hrow + (((ks*4 + g16) ^ (t & 7)) << 3));
  }

  auto stageA = [&](int s, char* dst) {
    const int i = s >> 2, kk = s & 3;
    const int rb0 = (o*16 + i)*65, rb1 = (256 + o*16 + i)*65;
    #pragma unroll
    for (int j = 0; j < 4; ++j) {
      int rr = wave*32 + j*8 + lrow8;
      int wrow = (rr < 64) ? (rb0 + rr) : (rb1 + (rr - 64));
      GLDS(wb + (((size_t)wrow*256 + kk*64) << 1) + lcol, dst + (wave*32 + j*8)*128);
    }
  };

  stageA(0, Al[0]);
  stageA(1, Al[1]);
  __syncthreads();                                   // drains Breg + both stages

  f32x4 yac[4][3] = {};
  f32x4 fac[4][3];
  half4 xv[4][3];
  half4 bh[4];
  const h16* b2ph = (const h16*)b2p;
  for (int i = 0; i < 16; ++i) {
    #pragma unroll
    for (int kk = 0; kk < 4; ++kk) {
      const int s = i*4 + kk;
      if (kk == 0) {                                 // 16 counted loads: X(i)+b2(i)
        const h16* Xrow = (const h16*)X16 + (size_t)(b*16 + i)*TP*136;
        #pragma unroll
        for (int mi = 0; mi < 4; ++mi) {
          int fb0 = mi*16 + g16*4;
          #pragma unroll
          for (int nt = 0; nt < 3; ++nt) {
            int t = t0 + wn*48 + nt*16 + l15;
            xv[mi][nt] = *(const half4*)(Xrow + (size_t)t*136 + wp*68 + fb0);
          }
          bh[mi] = *(const half4*)(b2ph + (size_t)((o*16 + i)*2 + wp)*64 + fb0);
        }
      }
      __builtin_amdgcn_sched_barrier(0);
      if (s == 63)     { asm volatile("s_waitcnt vmcnt(0)"  ::: "memory"); }
      else if (kk >= 2){ asm volatile("s_waitcnt vmcnt(8)"  ::: "memory"); }
      else             { asm volatile("s_waitcnt vmcnt(24)" ::: "memory"); }
      __builtin_amdgcn_s_barrier();
      __builtin_amdgcn_sched_barrier(0);
      if (s + 2 <= 63) stageA(s + 2, Al[(s + 2) % 3]);   // post-barrier: race-free
      __builtin_amdgcn_sched_barrier(0);
      if (kk == 0) {
        #pragma unroll
        for (int mi = 0; mi < 4; ++mi)
          #pragma unroll
          for (int nt = 0; nt < 3; ++nt)
            fac[mi][nt] = f32x4{0.f, 0.f, 0.f, 0.f};
      }
      const char* Ab = Al[s % 3];
      __builtin_amdgcn_s_setprio(1);
      #pragma unroll
      for (int ks2 = 0; ks2 < 2; ++ks2) {
        half8 Af[4];
        #pragma unroll
        for (int mi = 0; mi < 4; ++mi) {
          int rr = wp*64 + mi*16 + l15;
          Af[mi] = *(const half8*)(Ab + rr*128 + (((ks2*4 + g16) ^ (rr & 7)) << 4));
        }
        #pragma unroll
        for (int mi = 0; mi < 4; ++mi)
          #pragma unroll
          for (int nt = 0; nt < 3; ++nt)
            fac[mi][nt] = __builtin_amdgcn_mfma_f32_16x16x32_f16(Af[mi], Breg[nt][kk*2 + ks2], fac[mi][nt], 0,0,0);
      }
      __builtin_amdgcn_s_setprio(0);
      if (kk == 3) {                                 // X/b2 retired at kk2 entry wait
        #pragma unroll
        for (int mi = 0; mi < 4; ++mi)
          #pragma unroll
          for (int nt = 0; nt < 3; ++nt)
            #pragma unroll
            for (int e = 0; e < 4; ++e)
              yac[mi][nt][e] += (fac[mi][nt][e] + (float)bh[mi][e]) * (float)xv[mi][nt][e];
      }
    }
  }
  h16* Yh = (h16*)Y16;
  #pragma unroll
  for (int mi = 0; mi < 4; ++mi) {
    int fb0 = mi*16 + g16*4;
    #pragma unroll
    for (int nt = 0; nt < 3; ++nt) {
      int t = t0 + wn*48 + nt*16 + l15;
      if (t < NFR) {
        half4 v;
        v[0]=(h16)yac[mi][nt][0]; v[1]=(h16)yac[mi][nt][1];
        v[2]=(h16)yac[mi][nt][2]; v[3]=(h16)yac[mi][nt][3];
        *(half4*)(Yh + ((size_t)(b*16 + o)*NFR + t)*136 + wp*68 + fb0) = v;
      }
    }
  }
}

// fb=64 (Nyquist) slice
__launch_bounds__(256)
__global__ void dfc_edge(const float* __restrict__ w2, const float* __restrict__ b2,
                         const u16* __restrict__ hT16, const u16* __restrict__ X16,
                         u16* __restrict__ Y16) {
  __shared__ float Wl[8192];
  __shared__ float b2l[32];
  const int o = blockIdx.x, b = blockIdx.y, tc = blockIdx.z, tid = threadIdx.x;
  for (int idx = tid; idx < 8192; idx += 256) {
    int pi = idx >> 8, c = idx & 255;
    int p = pi >> 4, i = pi & 15;
    Wl[idx] = w2[(size_t)(((p*16 + o)*16 + i)*65 + 64)*256 + c];
  }
  if (tid < 32) {
    int p = tid >> 4, i = tid & 15;
    b2l[tid] = b2[(size_t)((p*16 + o)*16 + i)*65 + 64];
  }
  __syncthreads();
  const h16* hh = (const h16*)hT16;
  const h16* Xh = (const h16*)X16;
  h16* Yh = (h16*)Y16;
  for (int t = tc*256 + tid; t < NFR; t += 512) {
    int key = t & 7;
    float facc[32];
    #pragma unroll
    for (int pi = 0; pi < 32; ++pi) facc[pi] = b2l[pi];
    const h16* hrow = hh + ((size_t)b*TP + t)*256;
    for (int cc = 0; cc < 32; ++cc) {
      half8 hv = *(const half8*)(hrow + ((cc ^ key) << 3));
      float h0=(float)hv[0], h1=(float)hv[1], h2=(float)hv[2], h3=(float)hv[3];
      float h4=(float)hv[4], h5=(float)hv[5], h6=(float)hv[6], h7=(float)hv[7];
      #pragma unroll
      for (int pi = 0; pi < 32; ++pi) {
        const float* wr = &Wl[pi*256 + cc*8];
        facc[pi] += wr[0]*h0 + wr[1]*h1 + wr[2]*h2 + wr[3]*h3
                  + wr[4]*h4 + wr[5]*h5 + wr[6]*h6 + wr[7]*h7;
      }
    }
    float y0 = 0.f, y1 = 0.f;
    #pragma unroll
    for (int pi = 0; pi < 32; ++pi) {
      int p = pi >> 4, i = pi & 15;
      float xv = (float)Xh[((size_t)(b*16 + i)*TP + t)*136 + p*68 + 64];
      if (p == 0) y0 += facc[pi]*xv; else y1 += facc[pi]*xv;
    }
    Yh[((size_t)(b*16 + o)*NFR + t)*136 + 0*68 + 64] = (h16)y0;
    Yh[((size_t)(b*16 + o)*NFR + t)*136 + 1*68 + 64] = (h16)y1;
  }
}

// iSTFT: MFMA fr = Tist[128k x 136c] * Yl[136c x t], OLA in LDS
__launch_bounds__(256)
__global__ void dfc_istft(const u16* __restrict__ Y16, const float* __restrict__ wsp,
                          const float* __restrict__ bias, float* __restrict__ out) {
  __shared__ __align__(16) char YL[80*336];
  const int u = blockIdx.x, row = blockIdx.y, tid = threadIdx.x;
  const int wave = tid >> 6, lane = tid & 63;
  const int l15 = lane & 15, g16 = lane >> 4;
  for (int i = tid; i < 1680; i += 256) ((float4*)YL)[i] = float4{0.f,0.f,0.f,0.f};
  __syncthreads();
  const char* Yb = (const char*)Y16 + ((size_t)row*NFR + u*64)*272;
  for (int ch = tid; ch < 1105; ch += 256) {
    int tl = ch / 17, cc = ch - tl*17;
    float4 v = F4(Yb + (size_t)tl*272 + cc*16);
    *(float4*)(YL + tl*336 + cc*16) = v;
  }
  __syncthreads();
  const h16* Ti = (const h16*)(wsp + OFF_TI);
  f32x4 acc[2][5] = {};
  #pragma unroll
  for (int ks = 0; ks < 5; ++ks) {
    half8 Af[2];
    #pragma unroll
    for (int m = 0; m < 2; ++m)
      Af[m] = *(const half8*)(Ti + (size_t)((wave*2 + m)*16 + l15)*160 + ks*32 + g16*8);
    #pragma unroll
    for (int nt = 0; nt < 5; ++nt) {
      half8 Bf = *(const half8*)(YL + (nt*16 + l15)*336 + ks*64 + g16*16);
      acc[0][nt] = __builtin_amdgcn_mfma_f32_16x16x32_f16(Af[0], Bf, acc[0][nt], 0,0,0);
      acc[1][nt] = __builtin_amdgcn_mfma_f32_16x16x32_f16(Af[1], Bf, acc[1][nt], 0,0,0);
    }
  }
  __syncthreads();
  float* outT = (float*)YL;
  if (wave >= 2) {
    #pragma unroll
    for (int m = 0; m < 2; ++m) {
      int j0 = (wave*2 + m - 4)*16 + g16*4;
      #pragma unroll
      for (int nt = 0; nt < 4; ++nt) {
        int t = nt*16 + l15;
        *(f32x4*)&outT[t*68 + j0] = acc[m][nt];
      }
    }
  }
  __syncthreads();
  if (wave < 2) {
    #pragma unroll
    for (int m = 0; m < 2; ++m) {
      int j0 = (wave*2 + m)*16 + g16*4;
      #pragma unroll
      for (int nt = 0; nt < 5; ++nt) {
        int t = nt*16 + l15;
        if (t >= 1 && t <= 64) {
          f32x4 v = *(f32x4*)&outT[(t-1)*68 + j0];
          v[0] += acc[m][nt][0]; v[1] += acc[m][nt][1];
          v[2] += acc[m][nt][2]; v[3] += acc[m][nt][3];
          *(f32x4*)&outT[(t-1)*68 + j0] = v;
        }
      }
    }
  }
  __syncthreads();
  const float bv = bias[row & 15];
  float* og = out + (size_t)row*TLEN + (size_t)u*4096;
  #pragma unroll
  for (int r = 0; r < 4; ++r) {
    int fi = tid + 256*r;
    int sg = fi >> 4, jj = (fi & 15)*4;
    float4 v = *(float4*)&outT[sg*68 + jj];
    float4 w{v.x + bv, v.y + bv, v.z + bv, v.w + bv};
    *(float4*)(og + sg*64 + jj) = w;
  }
}

extern "C" void kernel_launch(void* const* d_in, const int* in_sizes, int n_in,
                              void* d_out, int out_size, void* d_ws, size_t ws_size,
                              hipStream_t stream) {
  (void)in_sizes; (void)n_in; (void)out_size; (void)ws_size;
  const float* x    = (const float*)d_in[0];
  const float* cond = (const float*)d_in[1];
  const float* w1   = (const float*)d_in[2];
  const float* b1   = (const float*)d_in[3];
  const float* w2   = (const float*)d_in[4];
  const float* b2   = (const float*)d_in[5];
  const float* bias = (const float*)d_in[6];
  float* ws  = (float*)d_ws;
  float* out = (float*)d_out;
  u16* R     = (u16*)(ws + OFF_R);      // hpart then w216
  u16* b2p   = (u16*)(ws + OFF_B2P);
  u16* hT16  = (u16*)(ws + OFF_HT);
  u16* X16   = (u16*)(ws + OFF_X16);
  u16* Y16   = (u16*)(ws + OFF_Y16);
  u16* w116  = (u16*)(ws + OFF_W116);

  (void)hipMemsetAsync(hT16, 0, (size_t)8*TP*256*2, stream);
  (void)hipMemsetAsync(X16, 0, (size_t)128*TP*136*2, stream);
  dfc_tables<<<dim3(1), dim3(256), 0, stream>>>(ws);
  dfc_prep_w1<<<dim3(2048), dim3(256), 0, stream>>>(w1, w116);
  dfc_conv1<<<dim3(9, 8, 8), dim3(512), 115200, stream>>>(cond, w116, R);
  dfc_hred<<<dim3(513), dim3(256), 0, stream>>>(R, b1, hT16);
  dfc_prep_w2<<<dim3(4160), dim3(256), 0, stream>>>(w2, R);
  dfc_prep_b2<<<dim3(128), dim3(256), 0, stream>>>(b2, b2p);
  dfc_stft<<<dim3(6, 128), dim3(256), 0, stream>>>(x, ws, X16);
  dfc_conv2y<<<dim3(6, 16, 8), dim3(256), 0, stream>>>(R, hT16, b2p, X16, Y16);
  dfc_edge<<<dim3(16, 8, 2), dim3(256), 0, stream>>>(w2, b2, hT16, X16, Y16);
  dfc_istft<<<dim3(8, 128), dim3(256), 0, stream>>>(Y16, ws, bias, out);
}

// Round 16
// 417.972 us; speedup vs baseline: 1.5456x; 1.5456x over previous
//
#include <hip/hip_runtime.h>
#include <math.h>

#define TLEN 32768
#define NFR  513
#define TP   576          // padded frame count
#define PI_F 3.14159265358979323846f

typedef unsigned short u16;
typedef unsigned int   u32;
typedef _Float16 h16;
typedef h16  half8  __attribute__((ext_vector_type(8)));
typedef h16  half4  __attribute__((ext_vector_type(4)));
typedef float f32x4 __attribute__((ext_vector_type(4)));

// float-unit offsets in workspace
#define OFF_TST  0         // Tst h16 [144][128]: stft DFT table (window folded)
#define OFF_TI   9216      // Tist h16 [128][160]: istft table, invden folded
#define OFF_B2P  19456     // b2p h16 [512][64]
#define OFF_R    35840     // hpart h16 [64][513][256] THEN w216 h16 [33280][256]
#define OFF_HT   4295680   // hT16 h16 [8][576][256], chunk-swizzled
#define OFF_X16  4885504   // X16 h16 [128][576][136]
#define OFF_Y16  9899008   // Y16 h16 [128][513][136]
#define OFF_W116 14364160  // w116s h16 [128ci][2 half][256co x 64k swizzled]
// end: 16,461,312 floats = 65.8 MB

#define F4(p) (*reinterpret_cast<const float4*>(p))
#define GLDS(gsrc, ldst) __builtin_amdgcn_global_load_lds( \
    (const __attribute__((address_space(1))) void*)(gsrc),  \
    (__attribute__((address_space(3))) void*)(ldst), 16, 0, 0)

__device__ __forceinline__ u16 pkh(float v) { return __builtin_bit_cast(u16, (h16)v); }

// merged prep: blocks [0,2048) w1->w116s; [2048,2176) b2->b2p; [2176,2240) tables
__launch_bounds__(256)
__global__ void dfc_prep(const float* __restrict__ w1, const float* __restrict__ b2,
                         float* __restrict__ ws, u16* __restrict__ w116,
                         u16* __restrict__ b2p) {
  const int blk = blockIdx.x, tid = threadIdx.x;
  if (blk < 2048) {                                  // w116s, XOR-swizzled
    int idx = blk*256 + tid;                         // < 524288
    int k8 = idx & 15, rc = idx >> 4;
    int co = rc & 255, ci = rc >> 8;
    const float* src = w1 + ((size_t)(co*128 + ci)*128 + k8*8);
    float4 a = F4(src), b = F4(src + 4);
    half8 hv;
    hv[0]=(h16)a.x; hv[1]=(h16)a.y; hv[2]=(h16)a.z; hv[3]=(h16)a.w;
    hv[4]=(h16)b.x; hv[5]=(h16)b.y; hv[6]=(h16)b.z; hv[7]=(h16)b.w;
    size_t dst = (size_t)ci*32768 + (k8 >> 3)*16384
               + co*64 + ((((k8 & 7) ^ (co & 7))) << 3);
    *(half8*)((h16*)w116 + dst) = hv;
  } else if (blk < 2176) {                           // b2p
    int idx = (blk - 2048)*256 + tid;                // < 32768
    int fb = idx & 63, r = idx >> 6;
    int p = r & 1, oi = r >> 1, o = oi >> 4, i = oi & 15;
    ((h16*)b2p)[idx] = (h16)b2[(size_t)((p*16 + o)*16 + i)*65 + fb];
  } else {                                           // tables over 64 blocks
    const int base = (blk - 2176)*256 + tid;
    u16* Ts = (u16*)(ws + OFF_TST);
    for (int idx = base; idx < 144*128; idx += 16384) {
      int c = idx >> 7, k = idx & 127;
      float v = 0.0f;
      if (c < 136) {
        int p = c / 68, fb = c - p*68;
        if (fb <= 64) {
          float wk = 0.5f*(1.0f - cosf(2.0f*PI_F*(float)k/128.0f));
          float ang = 2.0f*PI_F*(float)((fb*k) & 127)/128.0f;
          v = (p == 0) ? wk*cosf(ang) : -wk*sinf(ang);
        }
      }
      Ts[idx] = pkh(v);
    }
    u16* Ti = (u16*)(ws + OFF_TI);
    for (int idx = base; idx < 128*160; idx += 16384) {
      int k = idx / 160, c = idx - k*160;
      float v = 0.0f;
      if (c < 136) {
        int p = c / 68, fb = c - p*68;
        if (fb <= 64) {
          float wk = 0.5f*(1.0f - cosf(2.0f*PI_F*(float)k/128.0f));
          float cf = (fb == 0 || fb == 64) ? 1.0f : 2.0f;
          float sc = (1.0f/128.0f)*wk*cf;
          float ang = 2.0f*PI_F*(float)((fb*k) & 127)/128.0f;
          int j = k & 63;
          float w0 = 0.5f*(1.0f - cosf(2.0f*PI_F*(float)j/128.0f));
          float w1v = 0.5f*(1.0f - cosf(2.0f*PI_F*(float)(j+64)/128.0f));
          float inv = 1.0f/fmaxf(w0*w0 + w1v*w1v, 1e-11f);
          v = ((p == 0) ? sc*cosf(ang) : -sc*sinf(ang)) * inv;
        }
      }
      Ti[idx] = pkh(v);
    }
  }
}

// w216[row][c] = fp16(w2[row][c]) with in-row chunk swizzle: chunk c/8 ^ (fb&7)
// (must run AFTER hred: w216 region overlaps hpart)
__launch_bounds__(256)
__global__ void dfc_prep_w2(const float* __restrict__ w2, u16* __restrict__ w216) {
  int idx = blockIdx.x*256 + threadIdx.x;           // < 1064960
  int cc = idx & 31, r = idx >> 5;
  int fb = r % 65;
  const float* src = w2 + (size_t)r*256 + cc*8;
  float4 a = F4(src), b = F4(src + 4);
  half8 hv;
  hv[0]=(h16)a.x; hv[1]=(h16)a.y; hv[2]=(h16)a.z; hv[3]=(h16)a.w;
  hv[4]=(h16)b.x; hv[5]=(h16)b.y; hv[6]=(h16)b.z; hv[7]=(h16)b.w;
  *(half8*)((h16*)w216 + (size_t)r*256 + ((cc ^ (fb & 7)) << 3)) = hv;
}

// conv1 v8 (round-13 verbatim): A via GLDS ring-3 (1 barrier/phase, counted vmcnt),
// B reg-staged fp16 LDS. 512 thr, 256co x 64t, 32 phases.
__launch_bounds__(512, 2)
__global__ void dfc_conv1(const float* __restrict__ cond, const u16* __restrict__ w116,
                          u16* __restrict__ hpart) {
  extern __shared__ __align__(16) char LDS[];
  const int flat = (blockIdx.z*8 + blockIdx.y)*9 + blockIdx.x;
  const int kc = flat & 7;
  const int rest = flat >> 3;                       // 0..71
  const int b = rest / 9, tile = rest - b*9;
  const int t0 = tile*64;
  const int tid = threadIdx.x;
  const int wave = tid >> 6, lane = tid & 63;
  const int l15 = lane & 15, g16 = lane >> 4;
  const int gbase = t0*64 - 64;                     // f32 index
  const bool edge = (tile == 0) || (tile == 8);
  const char* wbB = (const char*)w116 + (size_t)kc*16*65536;
  const float* condB = cond + (size_t)(b*128 + kc*16)*TLEN;

  float4 rv[3];
  auto loadB = [&](int ci) {
    const float* cb = condB + (size_t)ci*TLEN;
    if (!edge) {
      rv[0] = F4(cb + gbase + 4*tid);
      rv[1] = F4(cb + gbase + 4*(512 + tid));
      rv[2] = F4(cb + gbase + 4*(1024 + (tid & 15)));
    } else {
      #pragma unroll
      for (int r = 0; r < 3; ++r) {
        int q = (r < 2) ? (r*512 + tid) : (1024 + (tid & 15));
        int g0 = gbase + 4*q;
        float4 v;
        v.x = (g0   >= 0 && g0   < TLEN) ? cb[g0]   : 0.f;
        v.y = (g0+1 >= 0 && g0+1 < TLEN) ? cb[g0+1] : 0.f;
        v.z = (g0+2 >= 0 && g0+2 < TLEN) ? cb[g0+2] : 0.f;
        v.w = (g0+3 >= 0 && g0+3 < TLEN) ? cb[g0+3] : 0.f;
        rv[r] = v;
      }
    }
  };
  auto writeB = [&](int bslot) {
    u32* seg = (u32*)(LDS + 98304 + bslot*8448);
    #pragma unroll
    for (int r = 0; r < 3; ++r) {
      if (r < 2 || tid < 16) {
        int q = (r < 2) ? (r*512 + tid) : (1024 + tid);
        int s2 = 2*q;
        int ph = s2 ^ (((s2 >> 5) & 7) << 2);
        uint2 pr;
        pr.x = (u32)pkh(rv[r].x) | ((u32)pkh(rv[r].y) << 16);
        pr.y = (u32)pkh(rv[r].z) | ((u32)pkh(rv[r].w) << 16);
        *reinterpret_cast<uint2*>(&seg[ph]) = pr;
      }
    }
  };
  auto stageA = [&](int p, int slot) {
    const char* src = wbB + (size_t)(p >> 1)*65536 + (p & 1)*32768 + wave*4096 + lane*16;
    char* dst = LDS + slot*32768 + wave*4096;
    GLDS(src,        dst);
    GLDS(src + 1024, dst + 1024);
    GLDS(src + 2048, dst + 2048);
    GLDS(src + 3072, dst + 3072);
  };

  loadB(0);
  stageA(0, 0); stageA(1, 1);
  if (edge) asm volatile("s_waitcnt vmcnt(0)" ::: "memory");
  else      asm volatile("s_waitcnt vmcnt(8)" ::: "memory");
  writeB(0);
  loadB(1);

  f32x4 acc[2][4] = {};
  for (int p = 0; p < 32; ++p) {
    const int ci = p >> 1, h = p & 1, sl = p % 3;
    if (edge || p >= 30) asm volatile("s_waitcnt vmcnt(0)" ::: "memory");
    else                 asm volatile("s_waitcnt vmcnt(7)" ::: "memory");
    asm volatile("s_waitcnt lgkmcnt(0)" ::: "memory");
    __builtin_amdgcn_s_barrier();
    __builtin_amdgcn_sched_barrier(0);
    if (p + 2 < 32) stageA(p + 2, (p + 2) % 3);
    if (h == 0 && ci + 1 < 16) {
      if (edge) asm volatile("s_waitcnt vmcnt(0)" ::: "memory");
      else      asm volatile("s_waitcnt vmcnt(4)" ::: "memory");
      writeB((ci + 1) & 1);
      if (ci + 2 < 16) loadB(ci + 2);
    }
    const char* Ab = LDS + sl*32768;
    const u32* seg = (const u32*)(LDS + 98304 + (ci & 1)*8448);
    __builtin_amdgcn_s_setprio(1);
    #pragma unroll
    for (int ks = 0; ks < 2; ++ks) {
      half8 Bf[4];
      #pragma unroll
      for (int nt = 0; nt < 4; ++nt) {
        int s2 = 32*(nt*16 + l15) + 32*h + 16*ks + 4*g16;
        int ph = s2 ^ (((s2 >> 5) & 7) << 2);
        Bf[nt] = *(const half8*)&seg[ph];
      }
      #pragma unroll
      for (int mi = 0; mi < 2; ++mi) {
        int co = wave*32 + mi*16 + l15;
        half8 Af = *(const half8*)(Ab + co*128 + (((ks*4 + g16) ^ (co & 7)) << 4));
        #pragma unroll
        for (int nt = 0; nt < 4; ++nt)
          acc[mi][nt] = __builtin_amdgcn_mfma_f32_16x16x32_f16(Af, Bf[nt], acc[mi][nt], 0,0,0);
      }
    }
    __builtin_amdgcn_s_setprio(0);
  }
  h16* hp = (h16*)hpart;
  #pragma unroll
  for (int mi = 0; mi < 2; ++mi) {
    const int co0 = wave*32 + mi*16 + g16*4;
    #pragma unroll
    for (int nt = 0; nt < 4; ++nt) {
      int t = t0 + nt*16 + l15;
      if (t < NFR) {
        half4 v;
        v[0]=(h16)acc[mi][nt][0]; v[1]=(h16)acc[mi][nt][1];
        v[2]=(h16)acc[mi][nt][2]; v[3]=(h16)acc[mi][nt][3];
        *(half4*)(hp + ((size_t)(kc*8 + b)*NFR + t)*256 + co0) = v;
      }
    }
  }
}

// reduce 8 partials + b1 -> hT16[b][t][c] fp16, chunk-swizzled (c/8 ^ (t&7))
__launch_bounds__(256)
__global__ void dfc_hred(const u16* __restrict__ hpart, const float* __restrict__ b1,
                         u16* __restrict__ hT16) {
  int idx = blockIdx.x*256 + threadIdx.x;            // < 131328
  int b = idx / 16416, r = idx % 16416;
  int t = r >> 5, cc = r & 31;
  float s[8];
  float4 ba = F4(&b1[cc*8]), bb = F4(&b1[cc*8 + 4]);
  s[0]=ba.x; s[1]=ba.y; s[2]=ba.z; s[3]=ba.w; s[4]=bb.x; s[5]=bb.y; s[6]=bb.z; s[7]=bb.w;
  const h16* hp = (const h16*)hpart;
  #pragma unroll
  for (int kc = 0; kc < 8; ++kc) {
    half8 hv = *(const half8*)(hp + ((size_t)(kc*8 + b)*NFR + t)*256 + cc*8);
    #pragma unroll
    for (int j = 0; j < 8; ++j) s[j] += (float)hv[j];
  }
  half8 o;
  #pragma unroll
  for (int j = 0; j < 8; ++j) o[j] = (h16)s[j];
  *(half8*)((h16*)hT16 + ((size_t)b*TP + t)*256 + ((cc ^ (t & 7)) << 3)) = o;
}

// stft v3 (MFMA): X[c=p*68+fb][t] = Tst[144x128] * frames[128k x 96t]
__launch_bounds__(256)
__global__ void dfc_stft(const float* __restrict__ x, const float* __restrict__ wsp,
                         u16* __restrict__ X16) {
  __shared__ __align__(16) u32 winu[3104];
  const int tile = blockIdx.x, row = blockIdx.y;
  const int t0 = (tile < 5) ? tile*96 : 417;
  const int tid = threadIdx.x;
  const int wave = tid >> 6, lane = tid & 63;
  const int wm = wave >> 1, wn = wave & 1;
  const int l15 = lane & 15, g16 = lane >> 4;
  const int gbase = t0*64 - 64;
  const bool edge = (tile == 0) || (tile == 5);
  const float* xb = x + (size_t)row*TLEN;

  #pragma unroll
  for (int r = 0; r < 7; ++r) {
    if (r < 6 || tid < 16) {
      int q = (r < 6) ? (tid + 256*r) : (1536 + tid);
      float4 v;
      if (!edge) {
        v = F4(xb + gbase + 4*q);
      } else {
        int g0 = gbase + 4*q;
        float e[4];
        #pragma unroll
        for (int j = 0; j < 4; ++j) {
          int g = g0 + j;
          int sidx = (g < 0) ? -g : ((g >= TLEN) ? (2*TLEN - 2 - g) : g);
          e[j] = xb[sidx];
        }
        v.x = e[0]; v.y = e[1]; v.z = e[2]; v.w = e[3];
      }
      int s2 = 2*q;
      int ph = s2 ^ (((s2 >> 5) & 7) << 2);
      uint2 pr;
      pr.x = (u32)pkh(v.x) | ((u32)pkh(v.y) << 16);
      pr.y = (u32)pkh(v.z) | ((u32)pkh(v.w) << 16);
      *reinterpret_cast<uint2*>(&winu[ph]) = pr;
    }
  }
  __syncthreads();
  const h16* Ts = (const h16*)(wsp + OFF_TST);
  f32x4 acc[5][3] = {};
  #pragma unroll
  for (int ks = 0; ks < 4; ++ks) {
    half8 Bf[3];
    #pragma unroll
    for (int nt = 0; nt < 3; ++nt) {
      int tl = (wn*3 + nt)*16 + l15;
      int s2 = 32*tl + 16*ks + 4*g16;
      int ph = s2 ^ (((s2 >> 5) & 7) << 2);
      Bf[nt] = *(const half8*)&winu[ph];
    }
    #pragma unroll
    for (int m = 0; m < 5; ++m) {
      int mi = wm*4 + m;
      half8 Af = *(const half8*)(Ts + (size_t)(mi*16 + l15)*128 + ks*32 + g16*8);
      #pragma unroll
      for (int nt = 0; nt < 3; ++nt)
        acc[m][nt] = __builtin_amdgcn_mfma_f32_16x16x32_f16(Af, Bf[nt], acc[m][nt], 0,0,0);
    }
  }
  h16* Xh = (h16*)X16;
  #pragma unroll
  for (int m = 0; m < 5; ++m) {
    int c0 = (wm*4 + m)*16 + g16*4;
    if (c0 < 136) {
      #pragma unroll
      for (int nt = 0; nt < 3; ++nt) {
        int t = t0 + (wn*3 + nt)*16 + l15;
        half4 v;
        v[0]=(h16)acc[m][nt][0]; v[1]=(h16)acc[m][nt][1];
        v[2]=(h16)acc[m][nt][2]; v[3]=(h16)acc[m][nt][3];
        *(half4*)(Xh + ((size_t)row*TP + t)*136 + c0) = v;
      }
    }
  }
}

// conv2y v3 (round-13 verbatim): B lane-resident; LDS = A-only 4-buffer, vmcnt(8).
__launch_bounds__(256, 2)
__global__ void dfc_conv2y(const u16* __restrict__ w216, const u16* __restrict__ hT16,
                           const u16* __restrict__ b2p, const u16* __restrict__ X16,
                           u16* __restrict__ Y16) {
  __shared__ __align__(16) char Al[4][16384];
  const int flat = (blockIdx.z*16 + blockIdx.y)*6 + blockIdx.x;
  const int b  = flat & 7;
  const int r2 = flat >> 3;
  const int o  = r2 / 6;
  const int t0 = (r2 - o*6) * 96;
  const int tid = threadIdx.x;
  const int wave = tid >> 6, lane = tid & 63;
  const int wp = wave >> 1, wn = wave & 1;
  const int l15 = lane & 15, g16 = lane >> 4;
  const int lrow8 = lane >> 3, lcol = (lane & 7)*16;
  const char* wb = (const char*)w216;

  half8 Breg[3][8];
  #pragma unroll
  for (int nt = 0; nt < 3; ++nt) {
    int t = t0 + wn*48 + nt*16 + l15;
    const h16* hrow = (const h16*)hT16 + ((size_t)b*TP + t)*256;
    #pragma unroll
    for (int ks = 0; ks < 8; ++ks)
      Breg[nt][ks] = *(const half8*)(hrow + (((ks*4 + g16) ^ (t & 7)) << 3));
  }

  auto stageA = [&](int s, char* dst) {
    const int i = s >> 2, kk = s & 3;
    const int rb0 = (o*16 + i)*65, rb1 = (256 + o*16 + i)*65;
    #pragma unroll
    for (int j = 0; j < 4; ++j) {
      int rr = wave*32 + j*8 + lrow8;
      int wrow = (rr < 64) ? (rb0 + rr) : (rb1 + (rr - 64));
      GLDS(wb + (((size_t)wrow*256 + kk*64) << 1) + lcol, dst + (wave*32 + j*8)*128);
    }
  };

  stageA(0, Al[0]);
  stageA(1, Al[1]);
  __syncthreads();

  f32x4 yac[4][3] = {};
  f32x4 fac[4][3];
  const h16* b2ph = (const h16*)b2p;
  for (int i = 0; i < 16; ++i) {
    #pragma unroll
    for (int mi = 0; mi < 4; ++mi) {
      half4 bh = *(const half4*)(b2ph + (size_t)((o*16 + i)*2 + wp)*64 + mi*16 + g16*4);
      #pragma unroll
      for (int nt = 0; nt < 3; ++nt) {
        fac[mi][nt][0] = (float)bh[0]; fac[mi][nt][1] = (float)bh[1];
        fac[mi][nt][2] = (float)bh[2]; fac[mi][nt][3] = (float)bh[3];
      }
    }
    #pragma unroll
    for (int kk = 0; kk < 4; ++kk) {
      const int s = i*4 + kk;
      if (s < 62) stageA(s + 2, Al[(kk + 2) & 3]);
      if (s < 62)      { asm volatile("s_waitcnt vmcnt(8)" ::: "memory"); }
      else if (s == 62){ asm volatile("s_waitcnt vmcnt(4)" ::: "memory"); }
      else             { asm volatile("s_waitcnt vmcnt(0)" ::: "memory"); }
      __builtin_amdgcn_s_barrier();
      __builtin_amdgcn_sched_barrier(0);
      const char* Ab = Al[kk];
      __builtin_amdgcn_s_setprio(1);
      #pragma unroll
      for (int ks2 = 0; ks2 < 2; ++ks2) {
        half8 Af[4];
        #pragma unroll
        for (int mi = 0; mi < 4; ++mi) {
          int rr = wp*64 + mi*16 + l15;
          Af[mi] = *(const half8*)(Ab + rr*128 + (((ks2*4 + g16) ^ (rr & 7)) << 4));
        }
        #pragma unroll
        for (int mi = 0; mi < 4; ++mi)
          #pragma unroll
          for (int nt = 0; nt < 3; ++nt)
            fac[mi][nt] = __builtin_amdgcn_mfma_f32_16x16x32_f16(Af[mi], Breg[nt][kk*2 + ks2], fac[mi][nt], 0,0,0);
      }
      __builtin_amdgcn_s_setprio(0);
    }
    const h16* Xrow = (const h16*)X16 + (size_t)(b*16 + i)*TP*136;
    #pragma unroll
    for (int mi = 0; mi < 4; ++mi) {
      int fb0 = mi*16 + g16*4;
      #pragma unroll
      for (int nt = 0; nt < 3; ++nt) {
        int t = t0 + wn*48 + nt*16 + l15;
        half4 xv = *(const half4*)(Xrow + (size_t)t*136 + wp*68 + fb0);
        yac[mi][nt][0] += fac[mi][nt][0]*(float)xv[0];
        yac[mi][nt][1] += fac[mi][nt][1]*(float)xv[1];
        yac[mi][nt][2] += fac[mi][nt][2]*(float)xv[2];
        yac[mi][nt][3] += fac[mi][nt][3]*(float)xv[3];
      }
    }
  }
  h16* Yh = (h16*)Y16;
  #pragma unroll
  for (int mi = 0; mi < 4; ++mi) {
    int fb0 = mi*16 + g16*4;
    #pragma unroll
    for (int nt = 0; nt < 3; ++nt) {
      int t = t0 + wn*48 + nt*16 + l15;
      if (t < NFR) {
        half4 v;
        v[0]=(h16)yac[mi][nt][0]; v[1]=(h16)yac[mi][nt][1];
        v[2]=(h16)yac[mi][nt][2]; v[3]=(h16)yac[mi][nt][3];
        *(half4*)(Yh + ((size_t)(b*16 + o)*NFR + t)*136 + wp*68 + fb0) = v;
      }
    }
  }
}

// fb=64 (Nyquist) slice
__launch_bounds__(256)
__global__ void dfc_edge(const float* __restrict__ w2, const float* __restrict__ b2,
                         const u16* __restrict__ hT16, const u16* __restrict__ X16,
                         u16* __restrict__ Y16) {
  __shared__ float Wl[8192];
  __shared__ float b2l[32];
  const int o = blockIdx.x, b = blockIdx.y, tc = blockIdx.z, tid = threadIdx.x;
  for (int idx = tid; idx < 8192; idx += 256) {
    int pi = idx >> 8, c = idx & 255;
    int p = pi >> 4, i = pi & 15;
    Wl[idx] = w2[(size_t)(((p*16 + o)*16 + i)*65 + 64)*256 + c];
  }
  if (tid < 32) {
    int p = tid >> 4, i = tid & 15;
    b2l[tid] = b2[(size_t)((p*16 + o)*16 + i)*65 + 64];
  }
  __syncthreads();
  const h16* hh = (const h16*)hT16;
  const h16* Xh = (const h16*)X16;
  h16* Yh = (h16*)Y16;
  for (int t = tc*256 + tid; t < NFR; t += 512) {
    int key = t & 7;
    float facc[32];
    #pragma unroll
    for (int pi = 0; pi < 32; ++pi) facc[pi] = b2l[pi];
    const h16* hrow = hh + ((size_t)b*TP + t)*256;
    for (int cc = 0; cc < 32; ++cc) {
      half8 hv = *(const half8*)(hrow + ((cc ^ key) << 3));
      float h0=(float)hv[0], h1=(float)hv[1], h2=(float)hv[2], h3=(float)hv[3];
      float h4=(float)hv[4], h5=(float)hv[5], h6=(float)hv[6], h7=(float)hv[7];
      #pragma unroll
      for (int pi = 0; pi < 32; ++pi) {
        const float* wr = &Wl[pi*256 + cc*8];
        facc[pi] += wr[0]*h0 + wr[1]*h1 + wr[2]*h2 + wr[3]*h3
                  + wr[4]*h4 + wr[5]*h5 + wr[6]*h6 + wr[7]*h7;
      }
    }
    float y0 = 0.f, y1 = 0.f;
    #pragma unroll
    for (int pi = 0; pi < 32; ++pi) {
      int p = pi >> 4, i = pi & 15;
      float xv = (float)Xh[((size_t)(b*16 + i)*TP + t)*136 + p*68 + 64];
      if (p == 0) y0 += facc[pi]*xv; else y1 += facc[pi]*xv;
    }
    Yh[((size_t)(b*16 + o)*NFR + t)*136 + 0*68 + 64] = (h16)y0;
    Yh[((size_t)(b*16 + o)*NFR + t)*136 + 1*68 + 64] = (h16)y1;
  }
}

// iSTFT: MFMA fr = Tist[128k x 136c] * Yl[136c x t], OLA in LDS
__launch_bounds__(256)
__global__ void dfc_istft(const u16* __restrict__ Y16, const float* __restrict__ wsp,
                          const float* __restrict__ bias, float* __restrict__ out) {
  __shared__ __align__(16) char YL[80*336];
  const int u = blockIdx.x, row = blockIdx.y, tid = threadIdx.x;
  const int wave = tid >> 6, lane = tid & 63;
  const int l15 = lane & 15, g16 = lane >> 4;
  for (int i = tid; i < 1680; i += 256) ((float4*)YL)[i] = float4{0.f,0.f,0.f,0.f};
  __syncthreads();
  const char* Yb = (const char*)Y16 + ((size_t)row*NFR + u*64)*272;
  for (int ch = tid; ch < 1105; ch += 256) {
    int tl = ch / 17, cc = ch - tl*17;
    float4 v = F4(Yb + (size_t)tl*272 + cc*16);
    *(float4*)(YL + tl*336 + cc*16) = v;
  }
  __syncthreads();
  const h16* Ti = (const h16*)(wsp + OFF_TI);
  f32x4 acc[2][5] = {};
  #pragma unroll
  for (int ks = 0; ks < 5; ++ks) {
    half8 Af[2];
    #pragma unroll
    for (int m = 0; m < 2; ++m)
      Af[m] = *(const half8*)(Ti + (size_t)((wave*2 + m)*16 + l15)*160 + ks*32 + g16*8);
    #pragma unroll
    for (int nt = 0; nt < 5; ++nt) {
      half8 Bf = *(const half8*)(YL + (nt*16 + l15)*336 + ks*64 + g16*16);
      acc[0][nt] = __builtin_amdgcn_mfma_f32_16x16x32_f16(Af[0], Bf, acc[0][nt], 0,0,0);
      acc[1][nt] = __builtin_amdgcn_mfma_f32_16x16x32_f16(Af[1], Bf, acc[1][nt], 0,0,0);
    }
  }
  __syncthreads();
  float* outT = (float*)YL;
  if (wave >= 2) {
    #pragma unroll
    for (int m = 0; m < 2; ++m) {
      int j0 = (wave*2 + m - 4)*16 + g16*4;
      #pragma unroll
      for (int nt = 0; nt < 4; ++nt) {
        int t = nt*16 + l15;
        *(f32x4*)&outT[t*68 + j0] = acc[m][nt];
      }
    }
  }
  __syncthreads();
  if (wave < 2) {
    #pragma unroll
    for (int m = 0; m < 2; ++m) {
      int j0 = (wave*2 + m)*16 + g16*4;
      #pragma unroll
      for (int nt = 0; nt < 5; ++nt) {
        int t = nt*16 + l15;
        if (t >= 1 && t <= 64) {
          f32x4 v = *(f32x4*)&outT[(t-1)*68 + j0];
          v[0] += acc[m][nt][0]; v[1] += acc[m][nt][1];
          v[2] += acc[m][nt][2]; v[3] += acc[m][nt][3];
          *(f32x4*)&outT[(t-1)*68 + j0] = v;
        }
      }
    }
  }
  __syncthreads();
  const float bv = bias[row & 15];
  float* og = out + (size_t)row*TLEN + (size_t)u*4096;
  #pragma unroll
  for (int r = 0; r < 4; ++r) {
    int fi = tid + 256*r;
    int sg = fi >> 4, jj = (fi & 15)*4;
    float4 v = *(float4*)&outT[sg*68 + jj];
    float4 w{v.x + bv, v.y + bv, v.z + bv, v.w + bv};
    *(float4*)(og + sg*64 + jj) = w;
  }
}

extern "C" void kernel_launch(void* const* d_in, const int* in_sizes, int n_in,
                              void* d_out, int out_size, void* d_ws, size_t ws_size,
                              hipStream_t stream) {
  (void)in_sizes; (void)n_in; (void)out_size; (void)ws_size;
  const float* x    = (const float*)d_in[0];
  const float* cond = (const float*)d_in[1];
  const float* w1   = (const float*)d_in[2];
  const float* b1   = (const float*)d_in[3];
  const float* w2   = (const float*)d_in[4];
  const float* b2   = (const float*)d_in[5];
  const float* bias = (const float*)d_in[6];
  float* ws  = (float*)d_ws;
  float* out = (float*)d_out;
  u16* R     = (u16*)(ws + OFF_R);      // hpart then w216
  u16* b2p   = (u16*)(ws + OFF_B2P);
  u16* hT16  = (u16*)(ws + OFF_HT);
  u16* X16   = (u16*)(ws + OFF_X16);
  u16* Y16   = (u16*)(ws + OFF_Y16);
  u16* w116  = (u16*)(ws + OFF_W116);

  (void)hipMemsetAsync(hT16, 0, (size_t)8*TP*256*2, stream);
  (void)hipMemsetAsync(X16, 0, (size_t)128*TP*136*2, stream);
  dfc_prep<<<dim3(2240), dim3(256), 0, stream>>>(w1, b2, ws, w116, b2p);
  dfc_conv1<<<dim3(9, 8, 8), dim3(512), 115200, stream>>>(cond, w116, R);
  dfc_hred<<<dim3(513), dim3(256), 0, stream>>>(R, b1, hT16);
  dfc_prep_w2<<<dim3(4160), dim3(256), 0, stream>>>(w2, R);
  dfc_stft<<<dim3(6, 128), dim3(256), 0, stream>>>(x, ws, X16);
  dfc_conv2y<<<dim3(6, 16, 8), dim3(256), 0, stream>>>(R, hT16, b2p, X16, Y16);
  dfc_edge<<<dim3(16, 8, 2), dim3(256), 0, stream>>>(w2, b2, hT16, X16, Y16);
  dfc_istft<<<dim3(8, 128), dim3(256), 0, stream>>>(Y16, ws, bias, out);
}

// Round 17
// 387.853 us; speedup vs baseline: 1.6656x; 1.0777x over previous
//
#include <hip/hip_runtime.h>
#include <math.h>

#define TLEN 32768
#define NFR  513
#define TP   576          // padded frame count
#define PI_F 3.14159265358979323846f

typedef unsigned short u16;
typedef unsigned int   u32;
typedef _Float16 h16;
typedef h16  half8  __attribute__((ext_vector_type(8)));
typedef h16  half4  __attribute__((ext_vector_type(4)));
typedef float f32x4 __attribute__((ext_vector_type(4)));

// float-unit offsets in workspace
#define OFF_TST  0         // Tst h16 [144][128]: stft DFT table (window folded)
#define OFF_TI   9216      // Tist h16 [128][160]: istft table, invden folded
#define OFF_B2P  19456     // b2p h16 [512][64]
#define OFF_R    35840     // hpart h16 [64][513][256] THEN w216 h16 [33280][256]
#define OFF_HT   4295680   // hT16 h16 [8][576][256], chunk-swizzled
#define OFF_X16  4885504   // X16 h16 [128][576][136]
#define OFF_Y16  9899008   // Y16 h16 [128][513][136]
#define OFF_W116 14364160  // w116s h16 [128ci][2 half][256co x 64k swizzled]
// end: 16,461,312 floats = 65.8 MB

#define F4(p) (*reinterpret_cast<const float4*>(p))
#define GLDS(gsrc, ldst) __builtin_amdgcn_global_load_lds( \
    (const __attribute__((address_space(1))) void*)(gsrc),  \
    (__attribute__((address_space(3))) void*)(ldst), 16, 0, 0)

__device__ __forceinline__ u16 pkh(float v) { return __builtin_bit_cast(u16, (h16)v); }

// merged prep: blocks [0,2048) w1->w116s; [2048,2176) b2->b2p; [2176,2240) tables
__launch_bounds__(256)
__global__ void dfc_prep(const float* __restrict__ w1, const float* __restrict__ b2,
                         float* __restrict__ ws, u16* __restrict__ w116,
                         u16* __restrict__ b2p) {
  const int blk = blockIdx.x, tid = threadIdx.x;
  if (blk < 2048) {                                  // w116s, XOR-swizzled
    int idx = blk*256 + tid;                         // < 524288
    int k8 = idx & 15, rc = idx >> 4;
    int co = rc & 255, ci = rc >> 8;
    const float* src = w1 + ((size_t)(co*128 + ci)*128 + k8*8);
    float4 a = F4(src), b = F4(src + 4);
    half8 hv;
    hv[0]=(h16)a.x; hv[1]=(h16)a.y; hv[2]=(h16)a.z; hv[3]=(h16)a.w;
    hv[4]=(h16)b.x; hv[5]=(h16)b.y; hv[6]=(h16)b.z; hv[7]=(h16)b.w;
    size_t dst = (size_t)ci*32768 + (k8 >> 3)*16384
               + co*64 + ((((k8 & 7) ^ (co & 7))) << 3);
    *(half8*)((h16*)w116 + dst) = hv;
  } else if (blk < 2176) {                           // b2p
    int idx = (blk - 2048)*256 + tid;                // < 32768
    int fb = idx & 63, r = idx >> 6;
    int p = r & 1, oi = r >> 1, o = oi >> 4, i = oi & 15;
    ((h16*)b2p)[idx] = (h16)b2[(size_t)((p*16 + o)*16 + i)*65 + fb];
  } else {                                           // tables over 64 blocks
    const int base = (blk - 2176)*256 + tid;
    u16* Ts = (u16*)(ws + OFF_TST);
    for (int idx = base; idx < 144*128; idx += 16384) {
      int c = idx >> 7, k = idx & 127;
      float v = 0.0f;
      if (c < 136) {
        int p = c / 68, fb = c - p*68;
        if (fb <= 64) {
          float wk = 0.5f*(1.0f - cosf(2.0f*PI_F*(float)k/128.0f));
          float ang = 2.0f*PI_F*(float)((fb*k) & 127)/128.0f;
          v = (p == 0) ? wk*cosf(ang) : -wk*sinf(ang);
        }
      }
      Ts[idx] = pkh(v);
    }
    u16* Ti = (u16*)(ws + OFF_TI);
    for (int idx = base; idx < 128*160; idx += 16384) {
      int k = idx / 160, c = idx - k*160;
      float v = 0.0f;
      if (c < 136) {
        int p = c / 68, fb = c - p*68;
        if (fb <= 64) {
          float wk = 0.5f*(1.0f - cosf(2.0f*PI_F*(float)k/128.0f));
          float cf = (fb == 0 || fb == 64) ? 1.0f : 2.0f;
          float sc = (1.0f/128.0f)*wk*cf;
          float ang = 2.0f*PI_F*(float)((fb*k) & 127)/128.0f;
          int j = k & 63;
          float w0 = 0.5f*(1.0f - cosf(2.0f*PI_F*(float)j/128.0f));
          float w1v = 0.5f*(1.0f - cosf(2.0f*PI_F*(float)(j+64)/128.0f));
          float inv = 1.0f/fmaxf(w0*w0 + w1v*w1v, 1e-11f);
          v = ((p == 0) ? sc*cosf(ang) : -sc*sinf(ang)) * inv;
        }
      }
      Ti[idx] = pkh(v);
    }
  }
}

// w216[row][c] = fp16(w2[row][c]) with in-row chunk swizzle: chunk c/8 ^ (fb&7)
// (must run AFTER hred: w216 region overlaps hpart)
__launch_bounds__(256)
__global__ void dfc_prep_w2(const float* __restrict__ w2, u16* __restrict__ w216) {
  int idx = blockIdx.x*256 + threadIdx.x;           // < 1064960
  int cc = idx & 31, r = idx >> 5;
  int fb = r % 65;
  const float* src = w2 + (size_t)r*256 + cc*8;
  float4 a = F4(src), b = F4(src + 4);
  half8 hv;
  hv[0]=(h16)a.x; hv[1]=(h16)a.y; hv[2]=(h16)a.z; hv[3]=(h16)a.w;
  hv[4]=(h16)b.x; hv[5]=(h16)b.y; hv[6]=(h16)b.z; hv[7]=(h16)b.w;
  *(half8*)((h16*)w216 + (size_t)r*256 + ((cc ^ (fb & 7)) << 3)) = hv;
}

// conv1 v9: A ring-2 + single B buffer (73,984 B -> 2 blocks/CU).
// B safety: writeB(ci+1) only after post-MFMA barrier at h==1 (all waves done
// reading B(ci)). A ring-2 prefetch-1 issued post-entry-barrier: slot (p+1)&1
// was last read at p-1, whose readers all passed p's entry barrier.
__launch_bounds__(512, 2)
__global__ void dfc_conv1(const float* __restrict__ cond, const u16* __restrict__ w116,
                          u16* __restrict__ hpart) {
  extern __shared__ __align__(16) char LDS[];       // 2*32768 + 8448 = 73984 B
  const int flat = (blockIdx.z*8 + blockIdx.y)*9 + blockIdx.x;
  const int kc = flat & 7;
  const int rest = flat >> 3;                       // 0..71
  const int b = rest / 9, tile = rest - b*9;
  const int t0 = tile*64;
  const int tid = threadIdx.x;
  const int wave = tid >> 6, lane = tid & 63;
  const int l15 = lane & 15, g16 = lane >> 4;
  const int gbase = t0*64 - 64;                     // f32 index
  const bool edge = (tile == 0) || (tile == 8);
  const char* wbB = (const char*)w116 + (size_t)kc*16*65536;
  const float* condB = cond + (size_t)(b*128 + kc*16)*TLEN;

  float4 rv[3];
  auto loadB = [&](int ci) {                        // 3 vm loads
    const float* cb = condB + (size_t)ci*TLEN;
    if (!edge) {
      rv[0] = F4(cb + gbase + 4*tid);
      rv[1] = F4(cb + gbase + 4*(512 + tid));
      rv[2] = F4(cb + gbase + 4*(1024 + (tid & 15)));
    } else {
      #pragma unroll
      for (int r = 0; r < 3; ++r) {
        int q = (r < 2) ? (r*512 + tid) : (1024 + (tid & 15));
        int g0 = gbase + 4*q;
        float4 v;
        v.x = (g0   >= 0 && g0   < TLEN) ? cb[g0]   : 0.f;
        v.y = (g0+1 >= 0 && g0+1 < TLEN) ? cb[g0+1] : 0.f;
        v.z = (g0+2 >= 0 && g0+2 < TLEN) ? cb[g0+2] : 0.f;
        v.w = (g0+3 >= 0 && g0+3 < TLEN) ? cb[g0+3] : 0.f;
        rv[r] = v;
      }
    }
  };
  auto writeB = [&]() {
    u32* seg = (u32*)(LDS + 65536);
    #pragma unroll
    for (int r = 0; r < 3; ++r) {
      if (r < 2 || tid < 16) {
        int q = (r < 2) ? (r*512 + tid) : (1024 + tid);
        int s2 = 2*q;
        int ph = s2 ^ (((s2 >> 5) & 7) << 2);
        uint2 pr;
        pr.x = (u32)pkh(rv[r].x) | ((u32)pkh(rv[r].y) << 16);
        pr.y = (u32)pkh(rv[r].z) | ((u32)pkh(rv[r].w) << 16);
        *reinterpret_cast<uint2*>(&seg[ph]) = pr;
      }
    }
  };
  auto stageA = [&](int p, int slot) {              // 4 GLDS
    const char* src = wbB + (size_t)(p >> 1)*65536 + (p & 1)*32768 + wave*4096 + lane*16;
    char* dst = LDS + slot*32768 + wave*4096;
    GLDS(src,        dst);
    GLDS(src + 1024, dst + 1024);
    GLDS(src + 2048, dst + 2048);
    GLDS(src + 3072, dst + 3072);
  };

  // prologue: B(0) -> LDS; A(0) in flight
  loadB(0);
  stageA(0, 0);
  if (edge) asm volatile("s_waitcnt vmcnt(0)" ::: "memory");
  else      asm volatile("s_waitcnt vmcnt(4)" ::: "memory");   // B0 regs done
  writeB();

  f32x4 acc[2][4] = {};
  for (int p = 0; p < 32; ++p) {
    const int ci = p >> 1, h = p & 1;
    if (edge || h == 0 || p == 31) asm volatile("s_waitcnt vmcnt(0)" ::: "memory");
    else                           asm volatile("s_waitcnt vmcnt(3)" ::: "memory");
    asm volatile("s_waitcnt lgkmcnt(0)" ::: "memory");
    __builtin_amdgcn_s_barrier();
    __builtin_amdgcn_sched_barrier(0);
    if (p + 1 < 32) stageA(p + 1, (p + 1) & 1);
    const char* Ab = LDS + (p & 1)*32768;
    const u32* seg = (const u32*)(LDS + 65536);
    __builtin_amdgcn_s_setprio(1);
    #pragma unroll
    for (int ks = 0; ks < 2; ++ks) {
      half8 Bf[4];
      #pragma unroll
      for (int nt = 0; nt < 4; ++nt) {
        int s2 = 32*(nt*16 + l15) + 32*h + 16*ks + 4*g16;
        int ph = s2 ^ (((s2 >> 5) & 7) << 2);
        Bf[nt] = *(const half8*)&seg[ph];
      }
      #pragma unroll
      for (int mi = 0; mi < 2; ++mi) {
        int co = wave*32 + mi*16 + l15;
        half8 Af = *(const half8*)(Ab + co*128 + (((ks*4 + g16) ^ (co & 7)) << 4));
        #pragma unroll
        for (int nt = 0; nt < 4; ++nt)
          acc[mi][nt] = __builtin_amdgcn_mfma_f32_16x16x32_f16(Af, Bf[nt], acc[mi][nt], 0,0,0);
      }
    }
    __builtin_amdgcn_s_setprio(0);
    if (h == 0) {
      if (ci + 1 < 16) loadB(ci + 1);
    } else if (ci + 1 < 16) {
      asm volatile("s_waitcnt lgkmcnt(0)" ::: "memory");
      __builtin_amdgcn_s_barrier();                 // all waves done reading B(ci)
      if (edge) asm volatile("s_waitcnt vmcnt(0)" ::: "memory");
      else      asm volatile("s_waitcnt vmcnt(4)" ::: "memory"); // B(ci+1) regs done
      writeB();
    }
  }
  h16* hp = (h16*)hpart;
  #pragma unroll
  for (int mi = 0; mi < 2; ++mi) {
    const int co0 = wave*32 + mi*16 + g16*4;
    #pragma unroll
    for (int nt = 0; nt < 4; ++nt) {
      int t = t0 + nt*16 + l15;
      if (t < NFR) {
        half4 v;
        v[0]=(h16)acc[mi][nt][0]; v[1]=(h16)acc[mi][nt][1];
        v[2]=(h16)acc[mi][nt][2]; v[3]=(h16)acc[mi][nt][3];
        *(half4*)(hp + ((size_t)(kc*8 + b)*NFR + t)*256 + co0) = v;
      }
    }
  }
}

// reduce 8 partials + b1 -> hT16[b][t][c] fp16, chunk-swizzled (c/8 ^ (t&7))
__launch_bounds__(256)
__global__ void dfc_hred(const u16* __restrict__ hpart, const float* __restrict__ b1,
                         u16* __restrict__ hT16) {
  int idx = blockIdx.x*256 + threadIdx.x;            // < 131328
  int b = idx / 16416, r = idx % 16416;
  int t = r >> 5, cc = r & 31;
  float s[8];
  float4 ba = F4(&b1[cc*8]), bb = F4(&b1[cc*8 + 4]);
  s[0]=ba.x; s[1]=ba.y; s[2]=ba.z; s[3]=ba.w; s[4]=bb.x; s[5]=bb.y; s[6]=bb.z; s[7]=bb.w;
  const h16* hp = (const h16*)hpart;
  #pragma unroll
  for (int kc = 0; kc < 8; ++kc) {
    half8 hv = *(const half8*)(hp + ((size_t)(kc*8 + b)*NFR + t)*256 + cc*8);
    #pragma unroll
    for (int j = 0; j < 8; ++j) s[j] += (float)hv[j];
  }
  half8 o;
  #pragma unroll
  for (int j = 0; j < 8; ++j) o[j] = (h16)s[j];
  *(half8*)((h16*)hT16 + ((size_t)b*TP + t)*256 + ((cc ^ (t & 7)) << 3)) = o;
}

// stft v3 (MFMA): X[c=p*68+fb][t] = Tst[144x128] * frames[128k x 96t]
__launch_bounds__(256)
__global__ void dfc_stft(const float* __restrict__ x, const float* __restrict__ wsp,
                         u16* __restrict__ X16) {
  __shared__ __align__(16) u32 winu[3104];
  const int tile = blockIdx.x, row = blockIdx.y;
  const int t0 = (tile < 5) ? tile*96 : 417;
  const int tid = threadIdx.x;
  const int wave = tid >> 6, lane = tid & 63;
  const int wm = wave >> 1, wn = wave & 1;
  const int l15 = lane & 15, g16 = lane >> 4;
  const int gbase = t0*64 - 64;
  const bool edge = (tile == 0) || (tile == 5);
  const float* xb = x + (size_t)row*TLEN;

  #pragma unroll
  for (int r = 0; r < 7; ++r) {
    if (r < 6 || tid < 16) {
      int q = (r < 6) ? (tid + 256*r) : (1536 + tid);
      float4 v;
      if (!edge) {
        v = F4(xb + gbase + 4*q);
      } else {
        int g0 = gbase + 4*q;
        float e[4];
        #pragma unroll
        for (int j = 0; j < 4; ++j) {
          int g = g0 + j;
          int sidx = (g < 0) ? -g : ((g >= TLEN) ? (2*TLEN - 2 - g) : g);
          e[j] = xb[sidx];
        }
        v.x = e[0]; v.y = e[1]; v.z = e[2]; v.w = e[3];
      }
      int s2 = 2*q;
      int ph = s2 ^ (((s2 >> 5) & 7) << 2);
      uint2 pr;
      pr.x = (u32)pkh(v.x) | ((u32)pkh(v.y) << 16);
      pr.y = (u32)pkh(v.z) | ((u32)pkh(v.w) << 16);
      *reinterpret_cast<uint2*>(&winu[ph]) = pr;
    }
  }
  __syncthreads();
  const h16* Ts = (const h16*)(wsp + OFF_TST);
  f32x4 acc[5][3] = {};
  #pragma unroll
  for (int ks = 0; ks < 4; ++ks) {
    half8 Bf[3];
    #pragma unroll
    for (int nt = 0; nt < 3; ++nt) {
      int tl = (wn*3 + nt)*16 + l15;
      int s2 = 32*tl + 16*ks + 4*g16;
      int ph = s2 ^ (((s2 >> 5) & 7) << 2);
      Bf[nt] = *(const half8*)&winu[ph];
    }
    #pragma unroll
    for (int m = 0; m < 5; ++m) {
      int mi = wm*4 + m;
      half8 Af = *(const half8*)(Ts + (size_t)(mi*16 + l15)*128 + ks*32 + g16*8);
      #pragma unroll
      for (int nt = 0; nt < 3; ++nt)
        acc[m][nt] = __builtin_amdgcn_mfma_f32_16x16x32_f16(Af, Bf[nt], acc[m][nt], 0,0,0);
    }
  }
  h16* Xh = (h16*)X16;
  #pragma unroll
  for (int m = 0; m < 5; ++m) {
    int c0 = (wm*4 + m)*16 + g16*4;
    if (c0 < 136) {
      #pragma unroll
      for (int nt = 0; nt < 3; ++nt) {
        int t = t0 + (wn*3 + nt)*16 + l15;
        half4 v;
        v[0]=(h16)acc[m][nt][0]; v[1]=(h16)acc[m][nt][1];
        v[2]=(h16)acc[m][nt][2]; v[3]=(h16)acc[m][nt][3];
        *(half4*)(Xh + ((size_t)row*TP + t)*136 + c0) = v;
      }
    }
  }
}

// conv2y v3 (round-13 verbatim): B lane-resident; LDS = A-only 4-buffer, vmcnt(8).
__launch_bounds__(256, 2)
__global__ void dfc_conv2y(const u16* __restrict__ w216, const u16* __restrict__ hT16,
                           const u16* __restrict__ b2p, const u16* __restrict__ X16,
                           u16* __restrict__ Y16) {
  __shared__ __align__(16) char Al[4][16384];
  const int flat = (blockIdx.z*16 + blockIdx.y)*6 + blockIdx.x;
  const int b  = flat & 7;
  const int r2 = flat >> 3;
  const int o  = r2 / 6;
  const int t0 = (r2 - o*6) * 96;
  const int tid = threadIdx.x;
  const int wave = tid >> 6, lane = tid & 63;
  const int wp = wave >> 1, wn = wave & 1;
  const int l15 = lane & 15, g16 = lane >> 4;
  const int lrow8 = lane >> 3, lcol = (lane & 7)*16;
  const char* wb = (const char*)w216;

  half8 Breg[3][8];
  #pragma unroll
  for (int nt = 0; nt < 3; ++nt) {
    int t = t0 + wn*48 + nt*16 + l15;
    const h16* hrow = (const h16*)hT16 + ((size_t)b*TP + t)*256;
    #pragma unroll
    for (int ks = 0; ks < 8; ++ks)
      Breg[nt][ks] = *(const half8*)(hrow + (((ks*4 + g16) ^ (t & 7)) << 3));
  }

  auto stageA = [&](int s, char* dst) {
    const int i = s >> 2, kk = s & 3;
    const int rb0 = (o*16 + i)*65, rb1 = (256 + o*16 + i)*65;
    #pragma unroll
    for (int j = 0; j < 4; ++j) {
      int rr = wave*32 + j*8 + lrow8;
      int wrow = (rr < 64) ? (rb0 + rr) : (rb1 + (rr - 64));
      GLDS(wb + (((size_t)wrow*256 + kk*64) << 1) + lcol, dst + (wave*32 + j*8)*128);
    }
  };

  stageA(0, Al[0]);
  stageA(1, Al[1]);
  __syncthreads();

  f32x4 yac[4][3] = {};
  f32x4 fac[4][3];
  const h16* b2ph = (const h16*)b2p;
  for (int i = 0; i < 16; ++i) {
    #pragma unroll
    for (int mi = 0; mi < 4; ++mi) {
      half4 bh = *(const half4*)(b2ph + (size_t)((o*16 + i)*2 + wp)*64 + mi*16 + g16*4);
      #pragma unroll
      for (int nt = 0; nt < 3; ++nt) {
        fac[mi][nt][0] = (float)bh[0]; fac[mi][nt][1] = (float)bh[1];
        fac[mi][nt][2] = (float)bh[2]; fac[mi][nt][3] = (float)bh[3];
      }
    }
    #pragma unroll
    for (int kk = 0; kk < 4; ++kk) {
      const int s = i*4 + kk;
      if (s < 62) stageA(s + 2, Al[(kk + 2) & 3]);
      if (s < 62)      { asm volatile("s_waitcnt vmcnt(8)" ::: "memory"); }
      else if (s == 62){ asm volatile("s_waitcnt vmcnt(4)" ::: "memory"); }
      else             { asm volatile("s_waitcnt vmcnt(0)" ::: "memory"); }
      __builtin_amdgcn_s_barrier();
      __builtin_amdgcn_sched_barrier(0);
      const char* Ab = Al[kk];
      __builtin_amdgcn_s_setprio(1);
      #pragma unroll
      for (int ks2 = 0; ks2 < 2; ++ks2) {
        half8 Af[4];
        #pragma unroll
        for (int mi = 0; mi < 4; ++mi) {
          int rr = wp*64 + mi*16 + l15;
          Af[mi] = *(const half8*)(Ab + rr*128 + (((ks2*4 + g16) ^ (rr & 7)) << 4));
        }
        #pragma unroll
        for (int mi = 0; mi < 4; ++mi)
          #pragma unroll
          for (int nt = 0; nt < 3; ++nt)
            fac[mi][nt] = __builtin_amdgcn_mfma_f32_16x16x32_f16(Af[mi], Breg[nt][kk*2 + ks2], fac[mi][nt], 0,0,0);
      }
      __builtin_amdgcn_s_setprio(0);
    }
    const h16* Xrow = (const h16*)X16 + (size_t)(b*16 + i)*TP*136;
    #pragma unroll
    for (int mi = 0; mi < 4; ++mi) {
      int fb0 = mi*16 + g16*4;
      #pragma unroll
      for (int nt = 0; nt < 3; ++nt) {
        int t = t0 + wn*48 + nt*16 + l15;
        half4 xv = *(const half4*)(Xrow + (size_t)t*136 + wp*68 + fb0);
        yac[mi][nt][0] += fac[mi][nt][0]*(float)xv[0];
        yac[mi][nt][1] += fac[mi][nt][1]*(float)xv[1];
        yac[mi][nt][2] += fac[mi][nt][2]*(float)xv[2];
        yac[mi][nt][3] += fac[mi][nt][3]*(float)xv[3];
      }
    }
  }
  h16* Yh = (h16*)Y16;
  #pragma unroll
  for (int mi = 0; mi < 4; ++mi) {
    int fb0 = mi*16 + g16*4;
    #pragma unroll
    for (int nt = 0; nt < 3; ++nt) {
      int t = t0 + wn*48 + nt*16 + l15;
      if (t < NFR) {
        half4 v;
        v[0]=(h16)yac[mi][nt][0]; v[1]=(h16)yac[mi][nt][1];
        v[2]=(h16)yac[mi][nt][2]; v[3]=(h16)yac[mi][nt][3];
        *(half4*)(Yh + ((size_t)(b*16 + o)*NFR + t)*136 + wp*68 + fb0) = v;
      }
    }
  }
}

// fb=64 (Nyquist) slice
__launch_bounds__(256)
__global__ void dfc_edge(const float* __restrict__ w2, const float* __restrict__ b2,
                         const u16* __restrict__ hT16, const u16* __restrict__ X16,
                         u16* __restrict__ Y16) {
  __shared__ float Wl[8192];
  __shared__ float b2l[32];
  const int o = blockIdx.x, b = blockIdx.y, tc = blockIdx.z, tid = threadIdx.x;
  for (int idx = tid; idx < 8192; idx += 256) {
    int pi = idx >> 8, c = idx & 255;
    int p = pi >> 4, i = pi & 15;
    Wl[idx] = w2[(size_t)(((p*16 + o)*16 + i)*65 + 64)*256 + c];
  }
  if (tid < 32) {
    int p = tid >> 4, i = tid & 15;
    b2l[tid] = b2[(size_t)((p*16 + o)*16 + i)*65 + 64];
  }
  __syncthreads();
  const h16* hh = (const h16*)hT16;
  const h16* Xh = (const h16*)X16;
  h16* Yh = (h16*)Y16;
  for (int t = tc*256 + tid; t < NFR; t += 512) {
    int key = t & 7;
    float facc[32];
    #pragma unroll
    for (int pi = 0; pi < 32; ++pi) facc[pi] = b2l[pi];
    const h16* hrow = hh + ((size_t)b*TP + t)*256;
    for (int cc = 0; cc < 32; ++cc) {
      half8 hv = *(const half8*)(hrow + ((cc ^ key) << 3));
      float h0=(float)hv[0], h1=(float)hv[1], h2=(float)hv[2], h3=(float)hv[3];
      float h4=(float)hv[4], h5=(float)hv[5], h6=(float)hv[6], h7=(float)hv[7];
      #pragma unroll
      for (int pi = 0; pi < 32; ++pi) {
        const float* wr = &Wl[pi*256 + cc*8];
        facc[pi] += wr[0]*h0 + wr[1]*h1 + wr[2]*h2 + wr[3]*h3
                  + wr[4]*h4 + wr[5]*h5 + wr[6]*h6 + wr[7]*h7;
      }
    }
    float y0 = 0.f, y1 = 0.f;
    #pragma unroll
    for (int pi = 0; pi < 32; ++pi) {
      int p = pi >> 4, i = pi & 15;
      float xv = (float)Xh[((size_t)(b*16 + i)*TP + t)*136 + p*68 + 64];
      if (p == 0) y0 += facc[pi]*xv; else y1 += facc[pi]*xv;
    }
    Yh[((size_t)(b*16 + o)*NFR + t)*136 + 0*68 + 64] = (h16)y0;
    Yh[((size_t)(b*16 + o)*NFR + t)*136 + 1*68 + 64] = (h16)y1;
  }
}

// iSTFT: MFMA fr = Tist[128k x 136c] * Yl[136c x t], OLA in LDS
__launch_bounds__(256)
__global__ void dfc_istft(const u16* __restrict__ Y16, const float* __restrict__ wsp,
                          const float* __restrict__ bias, float* __restrict__ out) {
  __shared__ __align__(16) char YL[80*336];
  const int u = blockIdx.x, row = blockIdx.y, tid = threadIdx.x;
  const int wave = tid >> 6, lane = tid & 63;
  const int l15 = lane & 15, g16 = lane >> 4;
  for (int i = tid; i < 1680; i += 256) ((float4*)YL)[i] = float4{0.f,0.f,0.f,0.f};
  __syncthreads();
  const char* Yb = (const char*)Y16 + ((size_t)row*NFR + u*64)*272;
  for (int ch = tid; ch < 1105; ch += 256) {
    int tl = ch / 17, cc = ch - tl*17;
    float4 v = F4(Yb + (size_t)tl*272 + cc*16);
    *(float4*)(YL + tl*336 + cc*16) = v;
  }
  __syncthreads();
  const h16* Ti = (const h16*)(wsp + OFF_TI);
  f32x4 acc[2][5] = {};
  #pragma unroll
  for (int ks = 0; ks < 5; ++ks) {
    half8 Af[2];
    #pragma unroll
    for (int m = 0; m < 2; ++m)
      Af[m] = *(const half8*)(Ti + (size_t)((wave*2 + m)*16 + l15)*160 + ks*32 + g16*8);
    #pragma unroll
    for (int nt = 0; nt < 5; ++nt) {
      half8 Bf = *(const half8*)(YL + (nt*16 + l15)*336 + ks*64 + g16*16);
      acc[0][nt] = __builtin_amdgcn_mfma_f32_16x16x32_f16(Af[0], Bf, acc[0][nt], 0,0,0);
      acc[1][nt] = __builtin_amdgcn_mfma_f32_16x16x32_f16(Af[1], Bf, acc[1][nt], 0,0,0);
    }
  }
  __syncthreads();
  float* outT = (float*)YL;
  if (wave >= 2) {
    #pragma unroll
    for (int m = 0; m < 2; ++m) {
      int j0 = (wave*2 + m - 4)*16 + g16*4;
      #pragma unroll
      for (int nt = 0; nt < 4; ++nt) {
        int t = nt*16 + l15;
        *(f32x4*)&outT[t*68 + j0] = acc[m][nt];
      }
    }
  }
  __syncthreads();
  if (wave < 2) {
    #pragma unroll
    for (int m = 0; m < 2; ++m) {
      int j0 = (wave*2 + m)*16 + g16*4;
      #pragma unroll
      for (int nt = 0; nt < 5; ++nt) {
        int t = nt*16 + l15;
        if (t >= 1 && t <= 64) {
          f32x4 v = *(f32x4*)&outT[(t-1)*68 + j0];
          v[0] += acc[m][nt][0]; v[1] += acc[m][nt][1];
          v[2] += acc[m][nt][2]; v[3] += acc[m][nt][3];
          *(f32x4*)&outT[(t-1)*68 + j0] = v;
        }
      }
    }
  }
  __syncthreads();
  const float bv = bias[row & 15];
  float* og = out + (size_t)row*TLEN + (size_t)u*4096;
  #pragma unroll
  for (int r = 0; r < 4; ++r) {
    int fi = tid + 256*r;
    int sg = fi >> 4, jj = (fi & 15)*4;
    float4 v = *(float4*)&outT[sg*68 + jj];
    float4 w{v.x + bv, v.y + bv, v.z + bv, v.w + bv};
    *(float4*)(og + sg*64 + jj) = w;
  }
}

extern "C" void kernel_launch(void* const* d_in, const int* in_sizes, int n_in,
                              void* d_out, int out_size, void* d_ws, size_t ws_size,
                              hipStream_t stream) {
  (void)in_sizes; (void)n_in; (void)out_size; (void)ws_size;
  const float* x    = (const float*)d_in[0];
  const float* cond = (const float*)d_in[1];
  const float* w1   = (const float*)d_in[2];
  const float* b1   = (const float*)d_in[3];
  const float* w2   = (const float*)d_in[4];
  const float* b2   = (const float*)d_in[5];
  const float* bias = (const float*)d_in[6];
  float* ws  = (float*)d_ws;
  float* out = (float*)d_out;
  u16* R     = (u16*)(ws + OFF_R);      // hpart then w216
  u16* b2p   = (u16*)(ws + OFF_B2P);
  u16* hT16  = (u16*)(ws + OFF_HT);
  u16* X16   = (u16*)(ws + OFF_X16);
  u16* Y16   = (u16*)(ws + OFF_Y16);
  u16* w116  = (u16*)(ws + OFF_W116);

  (void)hipMemsetAsync(hT16, 0, (size_t)8*TP*256*2, stream);
  (void)hipMemsetAsync(X16, 0, (size_t)128*TP*136*2, stream);
  dfc_prep<<<dim3(2240), dim3(256), 0, stream>>>(w1, b2, ws, w116, b2p);
  dfc_conv1<<<dim3(9, 8, 8), dim3(512), 73984, stream>>>(cond, w116, R);
  dfc_hred<<<dim3(513), dim3(256), 0, stream>>>(R, b1, hT16);
  dfc_prep_w2<<<dim3(4160), dim3(256), 0, stream>>>(w2, R);
  dfc_stft<<<dim3(6, 128), dim3(256), 0, stream>>>(x, ws, X16);
  dfc_conv2y<<<dim3(6, 16, 8), dim3(256), 0, stream>>>(R, hT16, b2p, X16, Y16);
  dfc_edge<<<dim3(16, 8, 2), dim3(256), 0, stream>>>(w2, b2, hT16, X16, Y16);
  dfc_istft<<<dim3(8, 128), dim3(256), 0, stream>>>(Y16, ws, bias, out);
}